// Round 6
// baseline (1758.415 us; speedup 1.0000x reference)
//
#include <hip/hip_runtime.h>

#define T_STEPS 512
#define HID     128

typedef _Float16 h4 __attribute__((ext_vector_type(4)));
typedef _Float16 v8hf __attribute__((ext_vector_type(8)));
typedef float v4f __attribute__((ext_vector_type(4)));

__device__ __forceinline__ float rcpf(float x) {
#if __has_builtin(__builtin_amdgcn_rcpf)
  return __builtin_amdgcn_rcpf(x);
#else
  return 1.0f / x;
#endif
}
__device__ __forceinline__ float sigm(float x)  { return rcpf(1.0f + __expf(-x)); }
__device__ __forceinline__ float tanh_f(float x){ return 1.0f - 2.0f * rcpf(__expf(2.0f * x) + 1.0f); }

// ---------------------------------------------------------------- prep ----
__global__ __launch_bounds__(256) void prep_w(
    const float* __restrict__ Wih0, const float* __restrict__ Whh0,
    const float* __restrict__ bih0, const float* __restrict__ bhh0,
    const float* __restrict__ Wih1, const float* __restrict__ Whh1,
    const float* __restrict__ bih1, const float* __restrict__ bhh1,
    _Float16* __restrict__ Wcat0, _Float16* __restrict__ Wcat1,
    float* __restrict__ bias0, float* __restrict__ bias1) {
  int i = blockIdx.x * blockDim.x + threadIdx.x;
  if (i < 512 * 192) {                  // Wcat0 row r: [Wih0(64) | Whh0(128)]
    int r = i / 192, k = i - r * 192;
    float v = (k < 64) ? Wih0[r * 64 + k] : Whh0[r * 128 + (k - 64)];
    Wcat0[i] = (_Float16)v;
  }
  if (i < 512 * 256) {                  // Wcat1 row r: [Wih1(128) | Whh1(128)]
    int r = i >> 8, k = i & 255;
    float v = (k < 128) ? Wih1[r * 128 + k] : Whh1[r * 128 + (k - 128)];
    Wcat1[i] = (_Float16)v;
  }
  if (i < 512) {
    bias0[i] = bih0[i] + bhh0[i];
    bias1[i] = bih1[i] + bhh1[i];
  }
}

// ------------------------------------------------------- fused LSTM ------
// 256 blocks x 512 threads (8 waves), 2 chains/block, BOTH layers per step.
// Per step: [act1(t-1) || MFMA0(t)] -> bar -> [act0(t) || x-refill] -> bar
//           -> MFMA1(t) -> bar.  h0 never leaves LDS; x burst-loaded
//           16 steps/refill into a 32-slot ring (no per-step global ops).
__global__ __launch_bounds__(512, 2) void lstm_fused(
    const float*    __restrict__ x,     // [B][T][64] fp32
    const _Float16* __restrict__ Wc0,   // [512][192]
    const _Float16* __restrict__ Wc1,   // [512][256]
    const float*    __restrict__ b0v,   // [512]
    const float*    __restrict__ b1v,   // [512]
    float*          __restrict__ h2last) { // [B][128] fp32
  __shared__ __align__(16) _Float16 xring[32][2][64];  // 8 KiB ring of x (fp16)
  __shared__ __align__(16) _Float16 h0sec[2][HID];
  __shared__ __align__(16) _Float16 h1sec[2][HID];
  __shared__ __align__(16) float gbuf0[2][512];
  __shared__ __align__(16) float gbuf1[2][512];

  const int tid  = threadIdx.x;
  const int lane = tid & 63;
  const int wv   = tid >> 6;          // 0..7
  const int m    = lane & 15;         // A row in tile / B col
  const int q    = lane >> 4;         // k-group / C row-quad
  const int ch   = m & 1;             // chain carried by this B col
  const int b0   = blockIdx.x * 2;

  // Weights resident: af0 4x6, af1 4x8 v8hf (compiler places in AGPR/VGPR)
  v8hf af0[4][6];
  v8hf af1[4][8];
  #pragma unroll
  for (int i = 0; i < 4; ++i) {
    const int rt = wv * 4 + i;
    #pragma unroll
    for (int kt = 0; kt < 6; ++kt)
      af0[i][kt] = *(const v8hf*)&Wc0[(rt * 16 + m) * 192 + kt * 32 + q * 8];
    #pragma unroll
    for (int kt = 0; kt < 8; ++kt)
      af1[i][kt] = *(const v8hf*)&Wc1[(rt * 16 + m) * 256 + kt * 32 + q * 8];
  }

  const int sc = tid >> 7, sd = tid & 127;     // state mapping (tid<256)
  float bi0 = 0, bf0 = 0, bg0 = 0, bo0 = 0;
  float bi1 = 0, bf1 = 0, bg1 = 0, bo1 = 0;
  if (tid < 256) {
    bi0 = b0v[sd]; bf0 = b0v[HID + sd]; bg0 = b0v[2*HID + sd]; bo0 = b0v[3*HID + sd];
    bi1 = b1v[sd]; bf1 = b1v[HID + sd]; bg1 = b1v[2*HID + sd]; bo1 = b1v[3*HID + sd];
    h0sec[sc][sd] = (_Float16)0.0f;
    h1sec[sc][sd] = (_Float16)0.0f;
  }
  {  // initial ring fill: slots 0..31 (steps 0..31), all 512 threads
    const int slot = tid >> 4, j = tid & 15;
    float4 a = *(const float4*)&x[((size_t)(b0 + 0) * T_STEPS + slot) * 64 + j * 4];
    float4 b = *(const float4*)&x[((size_t)(b0 + 1) * T_STEPS + slot) * 64 + j * 4];
    h4 ha; ha[0] = (_Float16)a.x; ha[1] = (_Float16)a.y;
           ha[2] = (_Float16)a.z; ha[3] = (_Float16)a.w;
    h4 hb; hb[0] = (_Float16)b.x; hb[1] = (_Float16)b.y;
           hb[2] = (_Float16)b.z; hb[3] = (_Float16)b.w;
    *(h4*)&xring[slot][0][j * 4] = ha;
    *(h4*)&xring[slot][1][j * 4] = hb;
  }
  __syncthreads();

  float c0 = 0.0f, c1 = 0.0f;

  for (int t = 0; t < T_STEPS; ++t) {
    // ---- Phase A: act1(t-1) on waves 0-3  ||  MFMA0(t) on all waves ----
    const bool refill = (tid >= 256) && ((t & 15) == 0) && (t >= 16) &&
                        (t + 16 < T_STEPS);
    float4 ra, rb;                       // refill loads issued early (hidden
    int rslot = 0;                       // under the MFMA0 phase)
    if (refill) {
      const int pid = tid - 256, s = pid >> 4, j = pid & 15;
      const int ts = t + 16 + s;
      rslot = ts & 31;
      ra = *(const float4*)&x[((size_t)(b0 + 0) * T_STEPS + ts) * 64 + j * 4];
      rb = *(const float4*)&x[((size_t)(b0 + 1) * T_STEPS + ts) * 64 + j * 4];
    }
    if (t > 0 && tid < 256) {            // act1(t-1)
      const float gi = gbuf1[sc][sd]         + bi1;
      const float gf = gbuf1[sc][HID + sd]   + bf1;
      const float gg = gbuf1[sc][2*HID + sd] + bg1;
      const float go = gbuf1[sc][3*HID + sd] + bo1;
      c1 = sigm(gf) * c1 + sigm(gi) * tanh_f(gg);
      h1sec[sc][sd] = (_Float16)(sigm(go) * tanh_f(c1));
    }
    {
      v4f acc[4];
      #pragma unroll
      for (int i = 0; i < 4; ++i) acc[i] = (v4f){0.f, 0.f, 0.f, 0.f};
      const int slot = t & 31;
      #pragma unroll
      for (int kt = 0; kt < 6; ++kt) {
        v8hf bfr = (kt < 2)
            ? *(const v8hf*)&xring[slot][ch][kt * 32 + q * 8]
            : *(const v8hf*)&h0sec[ch][kt * 32 + q * 8 - 64];
        #pragma unroll
        for (int i = 0; i < 4; ++i)
          acc[i] = __builtin_amdgcn_mfma_f32_16x16x32_f16(af0[i][kt], bfr, acc[i], 0, 0, 0);
      }
      if (m < 2) {
        #pragma unroll
        for (int i = 0; i < 4; ++i) {
          float4 o; o.x = acc[i][0]; o.y = acc[i][1]; o.z = acc[i][2]; o.w = acc[i][3];
          *(float4*)&gbuf0[m][(wv * 4 + i) * 16 + q * 4] = o;
        }
      }
    }
    __syncthreads();

    // ---- Phase B: act0(t) on waves 0-3  ||  ring refill on waves 4-7 ----
    if (tid < 256) {
      const float gi = gbuf0[sc][sd]         + bi0;
      const float gf = gbuf0[sc][HID + sd]   + bf0;
      const float gg = gbuf0[sc][2*HID + sd] + bg0;
      const float go = gbuf0[sc][3*HID + sd] + bo0;
      c0 = sigm(gf) * c0 + sigm(gi) * tanh_f(gg);
      h0sec[sc][sd] = (_Float16)(sigm(go) * tanh_f(c0));
    } else if (refill) {
      const int j = (tid - 256) & 15;
      h4 ha; ha[0] = (_Float16)ra.x; ha[1] = (_Float16)ra.y;
             ha[2] = (_Float16)ra.z; ha[3] = (_Float16)ra.w;
      h4 hb; hb[0] = (_Float16)rb.x; hb[1] = (_Float16)rb.y;
             hb[2] = (_Float16)rb.z; hb[3] = (_Float16)rb.w;
      *(h4*)&xring[rslot][0][j * 4] = ha;
      *(h4*)&xring[rslot][1][j * 4] = hb;
    }
    __syncthreads();

    // ---- Phase C: MFMA1(t) on all waves ----
    {
      v4f acc[4];
      #pragma unroll
      for (int i = 0; i < 4; ++i) acc[i] = (v4f){0.f, 0.f, 0.f, 0.f};
      #pragma unroll
      for (int kt = 0; kt < 8; ++kt) {
        v8hf bfr = (kt < 4)
            ? *(const v8hf*)&h0sec[ch][kt * 32 + q * 8]
            : *(const v8hf*)&h1sec[ch][kt * 32 + q * 8 - 128];
        #pragma unroll
        for (int i = 0; i < 4; ++i)
          acc[i] = __builtin_amdgcn_mfma_f32_16x16x32_f16(af1[i][kt], bfr, acc[i], 0, 0, 0);
      }
      if (m < 2) {
        #pragma unroll
        for (int i = 0; i < 4; ++i) {
          float4 o; o.x = acc[i][0]; o.y = acc[i][1]; o.z = acc[i][2]; o.w = acc[i][3];
          *(float4*)&gbuf1[m][(wv * 4 + i) * 16 + q * 4] = o;
        }
      }
    }
    __syncthreads();
  }

  // final act1(T-1) -> h2last
  if (tid < 256) {
    const float gi = gbuf1[sc][sd]         + bi1;
    const float gf = gbuf1[sc][HID + sd]   + bf1;
    const float gg = gbuf1[sc][2*HID + sd] + bg1;
    const float go = gbuf1[sc][3*HID + sd] + bo1;
    c1 = sigm(gf) * c1 + sigm(gi) * tanh_f(gg);
    h2last[(size_t)(b0 + sc) * HID + sd] = sigm(go) * tanh_f(c1);
  }
}

// ------------------------------------------------------------- fc head ----
__global__ __launch_bounds__(128) void fc_head(
    const float* __restrict__ h2last, const float* __restrict__ fc1w,
    const float* __restrict__ fc1b, const float* __restrict__ fc2w,
    const float* __restrict__ fc2b, float* __restrict__ out) {
  __shared__ float hb[128];
  __shared__ float part[2];
  const int b = blockIdx.x, j = threadIdx.x;
  hb[j] = h2last[(size_t)b * HID + j];
  __syncthreads();
  const float* wr = fc1w + j * HID;
  float acc = 0.f;
  #pragma unroll 8
  for (int d = 0; d < HID; ++d) acc += wr[d] * hb[d];
  float v = fmaxf(acc + fc1b[j], 0.f) * fc2w[j];
  #pragma unroll
  for (int s = 32; s > 0; s >>= 1) v += __shfl_down(v, s);
  if ((j & 63) == 0) part[j >> 6] = v;
  __syncthreads();
  if (j == 0) out[b] = part[0] + part[1] + fc2b[0];
}

// -------------------------------------------------------------- launch ----
extern "C" void kernel_launch(void* const* d_in, const int* in_sizes, int n_in,
                              void* d_out, int out_size, void* d_ws, size_t ws_size,
                              hipStream_t stream) {
  const float* x    = (const float*)d_in[0];
  const float* Wih0 = (const float*)d_in[1];
  const float* Whh0 = (const float*)d_in[2];
  const float* bih0 = (const float*)d_in[3];
  const float* bhh0 = (const float*)d_in[4];
  const float* Wih1 = (const float*)d_in[5];
  const float* Whh1 = (const float*)d_in[6];
  const float* bih1 = (const float*)d_in[7];
  const float* bhh1 = (const float*)d_in[8];
  const float* fc1w = (const float*)d_in[9];
  const float* fc1b = (const float*)d_in[10];
  const float* fc2w = (const float*)d_in[11];
  const float* fc2b = (const float*)d_in[12];
  float* out = (float*)d_out;

  char* ws = (char*)d_ws;
  const size_t OFF_WC0 = 0;                    // 512*192*2 = 196608
  const size_t OFF_WC1 = 196608;               // 512*256*2 = 262144
  const size_t OFF_B0  = OFF_WC1 + 262144;     // 512*4
  const size_t OFF_B1  = OFF_B0 + 2048;
  const size_t OFF_H2L = OFF_B1 + 2048;        // 512*128*4

  _Float16* Wcat0  = (_Float16*)(ws + OFF_WC0);
  _Float16* Wcat1  = (_Float16*)(ws + OFF_WC1);
  float*    bias0  = (float*)(ws + OFF_B0);
  float*    bias1  = (float*)(ws + OFF_B1);
  float*    h2last = (float*)(ws + OFF_H2L);

  prep_w<<<512, 256, 0, stream>>>(Wih0, Whh0, bih0, bhh0, Wih1, Whh1, bih1, bhh1,
                                  Wcat0, Wcat1, bias0, bias1);
  lstm_fused<<<256, 512, 0, stream>>>(x, Wcat0, Wcat1, bias0, bias1, h2last);
  fc_head<<<512, 128, 0, stream>>>(h2last, fc1w, fc1b, fc2w, fc2b, out);
}

// Round 7
// 1054.946 us; speedup vs baseline: 1.6668x; 1.6668x over previous
//
#include <hip/hip_runtime.h>

#define T_STEPS 512
#define HID     128

typedef _Float16 h4 __attribute__((ext_vector_type(4)));
typedef _Float16 v8hf __attribute__((ext_vector_type(8)));
typedef float v4f __attribute__((ext_vector_type(4)));

__device__ __forceinline__ float rcpf(float x) {
#if __has_builtin(__builtin_amdgcn_rcpf)
  return __builtin_amdgcn_rcpf(x);
#else
  return 1.0f / x;
#endif
}
__device__ __forceinline__ float sigm(float x)  { return rcpf(1.0f + __expf(-x)); }
__device__ __forceinline__ float tanh_f(float x){ return 1.0f - 2.0f * rcpf(__expf(2.0f * x) + 1.0f); }

// ---------------------------------------------------------------- prep ----
__global__ __launch_bounds__(256) void prep_w(
    const float* __restrict__ Wih0, const float* __restrict__ Whh0,
    const float* __restrict__ bih0, const float* __restrict__ bhh0,
    const float* __restrict__ Wih1, const float* __restrict__ Whh1,
    const float* __restrict__ bih1, const float* __restrict__ bhh1,
    _Float16* __restrict__ Wcat0, _Float16* __restrict__ Wcat1,
    float* __restrict__ bias0, float* __restrict__ bias1) {
  int i = blockIdx.x * blockDim.x + threadIdx.x;
  if (i < 512 * 192) {                  // Wcat0 row r: [Wih0(64) | Whh0(128)]
    int r = i / 192, k = i - r * 192;
    float v = (k < 64) ? Wih0[r * 64 + k] : Whh0[r * 128 + (k - 64)];
    Wcat0[i] = (_Float16)v;
  }
  if (i < 512 * 256) {                  // Wcat1 row r: [Wih1(128) | Whh1(128)]
    int r = i >> 8, k = i & 255;
    float v = (k < 128) ? Wih1[r * 128 + k] : Whh1[r * 128 + (k - 128)];
    Wcat1[i] = (_Float16)v;
  }
  if (i < 512) {
    bias0[i] = bih0[i] + bhh0[i];
    bias1[i] = bih1[i] + bhh1[i];
  }
}

// ------------------------------------------------------------- layer 0 ----
// 256 blocks x 512 threads (8 waves), 2 chains/block. v = [x(64)|h(128)].
// ZERO per-step global ops: x in 32-slot LDS ring (burst refill @ t%16==0),
// h history in 32-slot LDS ring (burst flush to hs0 @ t%16==8).
__global__ __launch_bounds__(512, 2) void lstm_l0(
    const float*    __restrict__ x,     // [B][T][64] fp32
    const _Float16* __restrict__ Wcat,  // [512][192]
    const float*    __restrict__ bias,  // [512]
    _Float16*       __restrict__ hs0) { // [B][T][128]
  __shared__ __align__(16) _Float16 xring[32][2][64];   // 8 KiB
  __shared__ __align__(16) _Float16 hist[32][2][HID];   // 16 KiB
  __shared__ __align__(16) _Float16 hsec[2][HID];       // 512 B
  __shared__ __align__(16) float gbuf[2][512];          // 4 KiB
  const int tid  = threadIdx.x;
  const int lane = tid & 63;
  const int wv   = tid >> 6;          // 0..7
  const int m    = lane & 15;         // A row in tile / B col
  const int q    = lane >> 4;         // k-group / C row-quad
  const int b0   = blockIdx.x * 2;

  v8hf af[4][6];
  #pragma unroll
  for (int i = 0; i < 4; ++i) {
    const int rt = wv * 4 + i;
    #pragma unroll
    for (int kt = 0; kt < 6; ++kt)
      af[i][kt] = *(const v8hf*)&Wcat[(rt * 16 + m) * 192 + kt * 32 + q * 8];
  }
  v4f cinit[4];                       // bias in MFMA C layout
  #pragma unroll
  for (int i = 0; i < 4; ++i) {
    float4 b4 = *(const float4*)&bias[(wv * 4 + i) * 16 + q * 4];
    cinit[i][0] = b4.x; cinit[i][1] = b4.y; cinit[i][2] = b4.z; cinit[i][3] = b4.w;
  }

  const int sc = tid >> 7, sd = tid & 127;   // act mapping (tid<256)
  if (tid < 256) hsec[sc][sd] = (_Float16)0.0f;

  {  // initial ring fill: steps 0..31; 512 items = 32 steps x 2 ch x 8 segs
    const int s = tid >> 4, c = (tid >> 3) & 1, seg = tid & 7;
    const float* src = &x[((size_t)(b0 + c) * T_STEPS + s) * 64 + seg * 8];
    float4 a = *(const float4*)src;
    float4 b = *(const float4*)(src + 4);
    v8hf o;
    o[0] = (_Float16)a.x; o[1] = (_Float16)a.y; o[2] = (_Float16)a.z; o[3] = (_Float16)a.w;
    o[4] = (_Float16)b.x; o[5] = (_Float16)b.y; o[6] = (_Float16)b.z; o[7] = (_Float16)b.w;
    *(v8hf*)&xring[s][c][seg * 8] = o;
  }
  __syncthreads();

  float c_state = 0.0f;

  for (int t = 0; t < T_STEPS; ++t) {
    // ---- phase A: (refill loads | flush stores) + MFMA ----
    const bool refill = ((t & 15) == 0) && (t >= 16) && (t + 16 < T_STEPS) &&
                        (tid >= 256);
    float4 ra, rb; int rs = 0, rc = 0, rseg = 0;
    if (refill) {        // 256 items: 16 steps x 2 ch x 8 segs
      const int it = tid - 256;
      rs = t + 16 + (it >> 4); rc = (it >> 3) & 1; rseg = it & 7;
      const float* src = &x[((size_t)(b0 + rc) * T_STEPS + rs) * 64 + rseg * 8];
      ra = *(const float4*)src;
      rb = *(const float4*)(src + 4);
    }
    if (((t & 15) == 8) && (t >= 24)) {  // flush steps t-24..t-9 (complete)
      const int fs = (t - 24) + (tid >> 5), fc = (tid >> 4) & 1, fseg = tid & 15;
      *(v8hf*)&hs0[((size_t)(b0 + fc) * T_STEPS + fs) * HID + fseg * 8] =
          *(const v8hf*)&hist[fs & 31][fc][fseg * 8];
    }
    {
      const int slot = t & 31;
      v4f acc[4];
      #pragma unroll
      for (int i = 0; i < 4; ++i) acc[i] = cinit[i];
      #pragma unroll
      for (int kt = 0; kt < 6; ++kt) {
        v8hf bfr = (kt < 2)
            ? *(const v8hf*)&xring[slot][m & 1][kt * 32 + q * 8]
            : *(const v8hf*)&hsec[m & 1][kt * 32 + q * 8 - 64];
        #pragma unroll
        for (int i = 0; i < 4; ++i)
          acc[i] = __builtin_amdgcn_mfma_f32_16x16x32_f16(af[i][kt], bfr, acc[i], 0, 0, 0);
      }
      if (m < 2) {
        #pragma unroll
        for (int i = 0; i < 4; ++i) {
          float4 o; o.x = acc[i][0]; o.y = acc[i][1]; o.z = acc[i][2]; o.w = acc[i][3];
          *(float4*)&gbuf[m][(wv * 4 + i) * 16 + q * 4] = o;
        }
      }
    }
    __syncthreads();                   // gates visible; ring reads done

    // ---- phase B: act (waves 0-3) | ring ds_write (refill lanes) ----
    if (tid < 256) {
      const float gi = gbuf[sc][sd];
      const float gf = gbuf[sc][HID + sd];
      const float gg = gbuf[sc][2 * HID + sd];
      const float go = gbuf[sc][3 * HID + sd];
      c_state = sigm(gf) * c_state + sigm(gi) * tanh_f(gg);
      const float hval = sigm(go) * tanh_f(c_state);
      const _Float16 hh = (_Float16)hval;
      hsec[sc][sd] = hh;
      hist[t & 31][sc][sd] = hh;
    } else if (refill) {
      v8hf o;
      o[0] = (_Float16)ra.x; o[1] = (_Float16)ra.y; o[2] = (_Float16)ra.z; o[3] = (_Float16)ra.w;
      o[4] = (_Float16)rb.x; o[5] = (_Float16)rb.y; o[6] = (_Float16)rb.z; o[7] = (_Float16)rb.w;
      *(v8hf*)&xring[rs & 31][rc][rseg * 8] = o;
    }
    __syncthreads();                   // h(t) + refilled x visible
  }
  {  // final flush: steps 496..511
    const int fs = 496 + (tid >> 5), fc = (tid >> 4) & 1, fseg = tid & 15;
    *(v8hf*)&hs0[((size_t)(b0 + fc) * T_STEPS + fs) * HID + fseg * 8] =
        *(const v8hf*)&hist[fs & 31][fc][fseg * 8];
  }
}

// ------------------------------------------------------------- layer 1 ----
// v = [h0(128) | h1(128)], K=256. h0 in 32-slot LDS ring, refill every 16.
__global__ __launch_bounds__(512, 2) void lstm_l1(
    const _Float16* __restrict__ hs0,   // [B][T][128]
    const _Float16* __restrict__ Wcat,  // [512][256]
    const float*    __restrict__ bias,  // [512]
    float*          __restrict__ h2last) { // [B][128] fp32
  __shared__ __align__(16) _Float16 h0ring[32][2][HID];  // 16 KiB
  __shared__ __align__(16) _Float16 h1sec[2][HID];
  __shared__ __align__(16) float gbuf[2][512];
  const int tid  = threadIdx.x;
  const int lane = tid & 63;
  const int wv   = tid >> 6;
  const int m    = lane & 15;
  const int q    = lane >> 4;
  const int b0   = blockIdx.x * 2;

  v8hf af[4][8];
  #pragma unroll
  for (int i = 0; i < 4; ++i) {
    const int rt = wv * 4 + i;
    #pragma unroll
    for (int kt = 0; kt < 8; ++kt)
      af[i][kt] = *(const v8hf*)&Wcat[(rt * 16 + m) * 256 + kt * 32 + q * 8];
  }
  v4f cinit[4];
  #pragma unroll
  for (int i = 0; i < 4; ++i) {
    float4 b4 = *(const float4*)&bias[(wv * 4 + i) * 16 + q * 4];
    cinit[i][0] = b4.x; cinit[i][1] = b4.y; cinit[i][2] = b4.z; cinit[i][3] = b4.w;
  }

  const int sc = tid >> 7, sd = tid & 127;
  if (tid < 256) h1sec[sc][sd] = (_Float16)0.0f;

  {  // initial ring fill: steps 0..31; 1024 items = 512 thr x 2
    #pragma unroll
    for (int r = 0; r < 2; ++r) {
      const int it = tid + r * 512;
      const int s = it >> 5, c = (it >> 4) & 1, seg = it & 15;
      *(v8hf*)&h0ring[s][c][seg * 8] =
          *(const v8hf*)&hs0[((size_t)(b0 + c) * T_STEPS + s) * HID + seg * 8];
    }
  }
  __syncthreads();

  float c_state = 0.0f;

  for (int t = 0; t < T_STEPS; ++t) {
    // ---- phase A: refill loads + MFMA ----
    const bool refill = ((t & 15) == 0) && (t >= 16) && (t + 16 < T_STEPS);
    v8hf rv; int rs = 0, rc = 0, rseg = 0;
    if (refill) {        // 512 items: 16 steps x 2 ch x 16 segs
      rs = t + 16 + (tid >> 5); rc = (tid >> 4) & 1; rseg = tid & 15;
      rv = *(const v8hf*)&hs0[((size_t)(b0 + rc) * T_STEPS + rs) * HID + rseg * 8];
    }
    {
      const int slot = t & 31;
      v4f acc[4];
      #pragma unroll
      for (int i = 0; i < 4; ++i) acc[i] = cinit[i];
      #pragma unroll
      for (int kt = 0; kt < 8; ++kt) {
        v8hf bfr = (kt < 4)
            ? *(const v8hf*)&h0ring[slot][m & 1][kt * 32 + q * 8]
            : *(const v8hf*)&h1sec[m & 1][kt * 32 + q * 8 - 128];
        #pragma unroll
        for (int i = 0; i < 4; ++i)
          acc[i] = __builtin_amdgcn_mfma_f32_16x16x32_f16(af[i][kt], bfr, acc[i], 0, 0, 0);
      }
      if (m < 2) {
        #pragma unroll
        for (int i = 0; i < 4; ++i) {
          float4 o; o.x = acc[i][0]; o.y = acc[i][1]; o.z = acc[i][2]; o.w = acc[i][3];
          *(float4*)&gbuf[m][(wv * 4 + i) * 16 + q * 4] = o;
        }
      }
    }
    __syncthreads();

    // ---- phase B: act (waves 0-3) | ring ds_write (all threads on refill) ----
    if (tid < 256) {
      const float gi = gbuf[sc][sd];
      const float gf = gbuf[sc][HID + sd];
      const float gg = gbuf[sc][2 * HID + sd];
      const float go = gbuf[sc][3 * HID + sd];
      c_state = sigm(gf) * c_state + sigm(gi) * tanh_f(gg);
      const float hval = sigm(go) * tanh_f(c_state);
      h1sec[sc][sd] = (_Float16)hval;
      if (t == T_STEPS - 1) h2last[(size_t)(b0 + sc) * HID + sd] = hval;
    }
    if (refill) *(v8hf*)&h0ring[rs & 31][rc][rseg * 8] = rv;
    __syncthreads();
  }
}

// ------------------------------------------------------------- fc head ----
__global__ __launch_bounds__(128) void fc_head(
    const float* __restrict__ h2last, const float* __restrict__ fc1w,
    const float* __restrict__ fc1b, const float* __restrict__ fc2w,
    const float* __restrict__ fc2b, float* __restrict__ out) {
  __shared__ float hb[128];
  __shared__ float part[2];
  const int b = blockIdx.x, j = threadIdx.x;
  hb[j] = h2last[(size_t)b * HID + j];
  __syncthreads();
  const float* wr = fc1w + j * HID;
  float acc = 0.f;
  #pragma unroll 8
  for (int d = 0; d < HID; ++d) acc += wr[d] * hb[d];
  float v = fmaxf(acc + fc1b[j], 0.f) * fc2w[j];
  #pragma unroll
  for (int s = 32; s > 0; s >>= 1) v += __shfl_down(v, s);
  if ((j & 63) == 0) part[j >> 6] = v;
  __syncthreads();
  if (j == 0) out[b] = part[0] + part[1] + fc2b[0];
}

// -------------------------------------------------------------- launch ----
extern "C" void kernel_launch(void* const* d_in, const int* in_sizes, int n_in,
                              void* d_out, int out_size, void* d_ws, size_t ws_size,
                              hipStream_t stream) {
  const float* x    = (const float*)d_in[0];
  const float* Wih0 = (const float*)d_in[1];
  const float* Whh0 = (const float*)d_in[2];
  const float* bih0 = (const float*)d_in[3];
  const float* bhh0 = (const float*)d_in[4];
  const float* Wih1 = (const float*)d_in[5];
  const float* Whh1 = (const float*)d_in[6];
  const float* bih1 = (const float*)d_in[7];
  const float* bhh1 = (const float*)d_in[8];
  const float* fc1w = (const float*)d_in[9];
  const float* fc1b = (const float*)d_in[10];
  const float* fc2w = (const float*)d_in[11];
  const float* fc2b = (const float*)d_in[12];
  float* out = (float*)d_out;

  char* ws = (char*)d_ws;
  const size_t OFF_HS0 = 0;                    // 512*512*128*2 = 64 MiB
  const size_t OFF_WC0 = 67108864;             // 512*192*2
  const size_t OFF_WC1 = OFF_WC0 + 196608;     // 512*256*2
  const size_t OFF_B0  = OFF_WC1 + 262144;     // 512*4
  const size_t OFF_B1  = OFF_B0 + 2048;
  const size_t OFF_H2L = OFF_B1 + 2048;        // 512*128*4

  _Float16* hs0    = (_Float16*)(ws + OFF_HS0);
  _Float16* Wcat0  = (_Float16*)(ws + OFF_WC0);
  _Float16* Wcat1  = (_Float16*)(ws + OFF_WC1);
  float*    bias0  = (float*)(ws + OFF_B0);
  float*    bias1  = (float*)(ws + OFF_B1);
  float*    h2last = (float*)(ws + OFF_H2L);

  prep_w<<<512, 256, 0, stream>>>(Wih0, Whh0, bih0, bhh0, Wih1, Whh1, bih1, bhh1,
                                  Wcat0, Wcat1, bias0, bias1);
  lstm_l0<<<256, 512, 0, stream>>>(x, Wcat0, bias0, hs0);
  lstm_l1<<<256, 512, 0, stream>>>(hs0, Wcat1, bias1, h2last);
  fc_head<<<512, 128, 0, stream>>>(h2last, fc1w, fc1b, fc2w, fc2b, out);
}